// Round 4
// baseline (1134.126 us; speedup 1.0000x reference)
//
#include <hip/hip_runtime.h>

#define NN 20000
#define NE 400000

typedef __attribute__((ext_vector_type(4))) float f32x4;
typedef _Float16 h2 __attribute__((ext_vector_type(2)));
typedef _Float16 h8 __attribute__((ext_vector_type(8)));

union H8 { h8 v; h2 p[4]; };

__device__ __forceinline__ float sigf(float x) { return 1.0f / (1.0f + __expf(-x)); }

__device__ __forceinline__ h8 rank1(_Float16 x, const h2 e[4]) {
    h2 xb = {x, x}; H8 f;
    #pragma unroll
    for (int j = 0; j < 4; ++j) f.p[j] = xb * e[j];
    return f.v;
}
__device__ __forceinline__ h8 rank3(_Float16 x0, _Float16 x1, _Float16 x2,
                                    const h2 e0[4], const h2 e1[4], const h2 e2[4]) {
    h2 x0b = {x0, x0}, x1b = {x1, x1}, x2b = {x2, x2}; H8 f;
    #pragma unroll
    for (int j = 0; j < 4; ++j) f.p[j] = x0b * e0[j] + x1b * e1[j] + x2b * e2[j];
    return f.v;
}
#define MFMA(a, b, c) __builtin_amdgcn_mfma_f32_16x16x32_f16(a, b, c, 0, 0, 0)

// ---------- weight prep: transpose + fp16 + fold norms: dst[w][K] = sc * src[K][w] ----------
__global__ void prep_kernel(const float* __restrict__ s1, const float* __restrict__ s2,
                            int K1, int Kt, int Nw, float sc1, float sc2,
                            unsigned short* __restrict__ dst, int total)
{
    int idx = blockIdx.x * 256 + threadIdx.x;
    if (idx >= total) return;
    int w = idx / Kt, K = idx - w * Kt;
    float v = (K < K1) ? s1[(size_t)K * Nw + w] * sc1
                       : s2[(size_t)(K - K1) * Nw + w] * sc2;
    _Float16 h = (_Float16)v;
    dst[idx] = __builtin_bit_cast(unsigned short, h);
}

// ---------- msg GEMM B helper (templated so k per M-tile is a literal) ----------
template<int MB>
__device__ __forceinline__ void msg_gemmB(
    int ln, int okt,
    const _Float16 (*s_xsh)[68], const _Float16 (*s_xv01)[66], const _Float16 (*s_xv2)[34],
    const _Float16 (*s_esh)[8], const _Float16 (*s_evTh)[7][8],
    const unsigned short* __restrict__ wB, f32x4 acc[6])
{
    const int k0 = (MB + 0) >> 1, k1 = (MB + 1) >> 1, k2 = (MB + 2) >> 1;
    const int ea = (((MB + 0) & 1) << 4) + ln;
    const int eb = (((MB + 1) & 1) << 4) + ln;
    const int ec = (((MB + 2) & 1) << 4) + ln;
    const unsigned short* b0p = wB + (size_t)ln * 768;
    const unsigned short* b1p = wB + (size_t)(16 + ln) * 768;

    h2 sv0[4], sv1[4], sv2[4], es0[4], es1[4], es2[4];
    #pragma unroll
    for (int j = 0; j < 4; ++j) {
        sv0[j] = ((const h2*)s_evTh[ea][k0])[j];
        sv1[j] = ((const h2*)s_evTh[eb][k1])[j];
        sv2[j] = ((const h2*)s_evTh[ec][k2])[j];
        es0[j] = ((const h2*)s_esh[ea])[j];
        es1[j] = ((const h2*)s_esh[eb])[j];
        es2[j] = ((const h2*)s_esh[ec])[j];
    }
    // sv region: z = xs[u]*ev[v][k]
    #pragma unroll 4
    for (int ks = 0; ks < 16; ++ks) {
        int ko = ks * 32 + okt * 8, u = ks * 4 + okt;
        h8 b0 = *(const h8*)(b0p + ko), b1 = *(const h8*)(b1p + ko);
        h8 a0 = rank1(s_xsh[ea][u], sv0);
        h8 a1 = rank1(s_xsh[eb][u], sv1);
        h8 a2 = rank1(s_xsh[ec][u], sv2);
        acc[0] = MFMA(a0, b0, acc[0]); acc[1] = MFMA(a0, b1, acc[1]);
        acc[2] = MFMA(a1, b0, acc[2]); acc[3] = MFMA(a1, b1, acc[3]);
        acc[4] = MFMA(a2, b0, acc[4]); acc[5] = MFMA(a2, b1, acc[5]);
    }
    // vs region: z = xv[u][k]*es[v]
    #pragma unroll 4
    for (int ks = 0; ks < 8; ++ks) {
        int ko = 512 + ks * 32 + okt * 8, u = ks * 4 + okt;
        h8 b0 = *(const h8*)(b0p + ko), b1 = *(const h8*)(b1p + ko);
        _Float16 xa = (k0 == 0) ? s_xv01[ea][u * 2] : (k0 == 1 ? s_xv01[ea][u * 2 + 1] : s_xv2[ea][u]);
        _Float16 xb = (k1 == 0) ? s_xv01[eb][u * 2] : (k1 == 1 ? s_xv01[eb][u * 2 + 1] : s_xv2[eb][u]);
        _Float16 xc = (k2 == 0) ? s_xv01[ec][u * 2] : (k2 == 1 ? s_xv01[ec][u * 2 + 1] : s_xv2[ec][u]);
        h8 a0 = rank1(xa, es0);
        h8 a1 = rank1(xb, es1);
        h8 a2 = rank1(xc, es2);
        acc[0] = MFMA(a0, b0, acc[0]); acc[1] = MFMA(a0, b1, acc[1]);
        acc[2] = MFMA(a1, b0, acc[2]); acc[3] = MFMA(a1, b1, acc[3]);
        acc[4] = MFMA(a2, b0, acc[4]); acc[5] = MFMA(a2, b1, acc[5]);
    }
}

// =============== message kernel: 32 edges/block, reg-frag fp16 MFMA, M-split waves ===============
__global__ __launch_bounds__(256, 5)
void msg_kernel(const float* __restrict__ nf, const float* __restrict__ ea,
                const int* __restrict__ eidx,
                const unsigned short* __restrict__ wA,   // [96][768] fp16, norms folded
                const unsigned short* __restrict__ wB,   // [32][768] fp16, norms folded
                float* __restrict__ agg)
{
    const int e0 = blockIdx.x * 32;
    const int t = threadIdx.x;
    const int wid = t >> 6, lane = t & 63, ln = lane & 15, okt = lane >> 4;

    __shared__ __align__(16) _Float16 s_xsh[32][68];
    __shared__ __align__(16) _Float16 s_xv01[32][66];   // [e][u*2+k] k<2
    __shared__ __align__(16) _Float16 s_xv2[32][34];    // [e][u] k=2
    __shared__ __align__(16) _Float16 s_esh[32][8];
    __shared__ __align__(16) _Float16 s_evTh[32][7][8]; // [e][k][v]
    __shared__ float s_gate[32][33];
    __shared__ int s_row[32], s_col[32];

    if (t < 32) s_row[t] = eidx[e0 + t];
    else if (t < 64) s_col[t - 32] = eidx[NE + e0 + (t - 32)];
    for (int i = t; i < 32 * 32; i += 256) {
        int e = i >> 5, c = i & 31;
        float v = ea[(size_t)(e0 + e) * 32 + c];
        if (c < 8) s_esh[e][c] = (_Float16)v;
        else { int d = c - 8; s_evTh[e][d % 3][d / 3] = (_Float16)v; }
    }
    __syncthreads();
    for (int i = t; i < 32 * 40; i += 256) {
        int e = i / 40, q = i - e * 40;
        f32x4 f4 = *((const f32x4*)nf + (size_t)s_col[e] * 40 + q);
        if (q < 16) {
            #pragma unroll
            for (int j = 0; j < 4; ++j) s_xsh[e][q * 4 + j] = (_Float16)f4[j];
        } else {
            #pragma unroll
            for (int j = 0; j < 4; ++j) {
                int d = (q - 16) * 4 + j, u = d / 3, k = d - u * 3;
                if (k < 2) s_xv01[e][u * 2 + k] = (_Float16)f4[j];
                else       s_xv2[e][u] = (_Float16)f4[j];
            }
        }
    }
    __syncthreads();

    f32x4 acc[6] = {};

    if (wid < 2) {
        // GEMM A: hs[32x96]; this wave: edges wid*16..+15, all 6 N-tiles
        const int e = wid * 16 + ln;
        const unsigned short* wb = wA + (size_t)ln * 768;
        h2 esv[4];
        #pragma unroll
        for (int j = 0; j < 4; ++j) esv[j] = ((const h2*)s_esh[e])[j];
        #pragma unroll 4
        for (int ks = 0; ks < 16; ++ks) {          // ss: xs[u]*es[v]
            int ko = ks * 32 + okt * 8, u = ks * 4 + okt;
            h8 a = rank1(s_xsh[e][u], esv);
            #pragma unroll
            for (int j = 0; j < 6; ++j)
                acc[j] = MFMA(a, *(const h8*)(wb + j * 16 * 768 + ko), acc[j]);
        }
        h2 e0v[4], e1v[4], e2v[4];
        #pragma unroll
        for (int j = 0; j < 4; ++j) {
            e0v[j] = ((const h2*)s_evTh[e][0])[j];
            e1v[j] = ((const h2*)s_evTh[e][1])[j];
            e2v[j] = ((const h2*)s_evTh[e][2])[j];
        }
        #pragma unroll 4
        for (int ks = 0; ks < 8; ++ks) {           // dd: sum_k xv[u][k]*ev[v][k]
            int ko = 512 + ks * 32 + okt * 8, u = ks * 4 + okt;
            h2 x01 = *(const h2*)&s_xv01[e][u * 2];
            h8 a = rank3(x01[0], x01[1], s_xv2[e][u], e0v, e1v, e2v);
            #pragma unroll
            for (int j = 0; j < 6; ++j)
                acc[j] = MFMA(a, *(const h8*)(wb + j * 16 * 768 + ko), acc[j]);
        }
    } else if (wid == 2) {
        msg_gemmB<0>(ln, okt, s_xsh, s_xv01, s_xv2, s_esh, s_evTh, wB, acc);
    } else {
        msg_gemmB<3>(ln, okt, s_xsh, s_xv01, s_xv2, s_esh, s_evTh, wB, acc);
    }

    // ---- epilogue: gate + scatter ----
    if (wid < 2) {
        #pragma unroll
        for (int j = 0; j < 6; ++j)
            #pragma unroll
            for (int r = 0; r < 4; ++r) {
                int e = wid * 16 + okt * 4 + r;
                float h = acc[j][r];
                if (j < 4) atomicAdd(agg + (size_t)s_row[e] * 160 + j * 16 + ln, h * sigf(h));
                else       s_gate[e][(j - 4) * 16 + ln] = sigf(h);
            }
    }
    __syncthreads();
    if (wid >= 2) {
        int mb = (wid - 2) * 3;
        #pragma unroll
        for (int m = 0; m < 3; ++m) {
            int mm = mb + m, k = mm >> 1;
            #pragma unroll
            for (int tt = 0; tt < 2; ++tt)
                #pragma unroll
                for (int r = 0; r < 4; ++r) {
                    int e = ((mm & 1) << 4) + okt * 4 + r;
                    int w2 = tt * 16 + ln;
                    atomicAdd(agg + (size_t)s_row[e] * 160 + 64 + w2 * 3 + k,
                              acc[m * 2 + tt][r] * s_gate[e][w2]);
                }
        }
    }
}

// =============== update kernel: 16 nodes/block, folded agglin, K-split waves ===============
__global__ __launch_bounds__(256, 4)
void upd_kernel(const float* __restrict__ nf, const float* __restrict__ agg,
                const unsigned short* __restrict__ wA,   // [96][7168] fp16
                const unsigned short* __restrict__ wB,   // [32][5120] fp16
                const float* __restrict__ Wlms, const float* __restrict__ Wlmv,
                const float* __restrict__ Wls, const float* __restrict__ Wlv,
                float* __restrict__ out)
{
    const int n0 = blockIdx.x * 16;
    const int t = threadIdx.x;
    const int wid = t >> 6, lane = t & 63, ln = lane & 15, okt = lane >> 4;

    __shared__ __align__(16) _Float16 s_xsh[16][68];
    __shared__ __align__(16) _Float16 s_xv01[16][66];
    __shared__ __align__(16) _Float16 s_xv2[16][34];
    __shared__ __align__(16) _Float16 s_ash[16][104];     // ags fp16
    __shared__ __align__(16) _Float16 s_avTh[16][3][40];  // agv^T fp16
    __shared__ float s_hs2[16][100];
    __shared__ float s_hv2[48][34];                       // rows (k*16+n)
    __shared__ float s_ag[16][160];

    for (int i = t; i < 16 * 160; i += 256)
        ((float*)s_ag)[i] = agg[(size_t)n0 * 160 + i];
    for (int i = t; i < 16 * 40; i += 256) {
        int n = i / 40, q = i - n * 40;
        f32x4 f4 = *((const f32x4*)nf + (size_t)(n0 + n) * 40 + q);
        if (q < 16) {
            #pragma unroll
            for (int j = 0; j < 4; ++j) s_xsh[n][q * 4 + j] = (_Float16)f4[j];
        } else {
            #pragma unroll
            for (int j = 0; j < 4; ++j) {
                int d = (q - 16) * 4 + j, u = d / 3, k = d - u * 3;
                if (k < 2) s_xv01[n][u * 2 + k] = (_Float16)f4[j];
                else       s_xv2[n][u] = (_Float16)f4[j];
            }
        }
    }
    __syncthreads();
    // folded agglin (linear commuted past segment_sum)
    #pragma unroll
    for (int r = 0; r < 6; ++r) {
        int o = t + r * 256;
        int n = o / 96, q = o - n * 96;
        float a = 0.f;
        #pragma unroll
        for (int u = 0; u < 64; ++u) a = fmaf(s_ag[n][u], Wlms[u * 96 + q], a);
        s_ash[n][q] = (_Float16)(a * 0.125f);
    }
    #pragma unroll
    for (int r = 0; r < 6; ++r) {
        int o = t + r * 256;
        int n = o / 96, q = o - n * 96, k = q >> 5, v = q & 31;
        float a = 0.f;
        #pragma unroll
        for (int u = 0; u < 32; ++u) a = fmaf(s_ag[n][64 + u * 3 + k], Wlmv[u * 32 + v], a);
        s_avTh[n][k][v] = (_Float16)(a * 0.17677669529663687f);
    }
    __syncthreads();

    f32x4 acc[6] = {};

    if (wid < 2) {
        // GEMM A: hs2[16x96], K=7168 split between wid 0 (0..3583) and wid 1 (3584..7167)
        const unsigned short* wb = wA + (size_t)ln * 7168;
        const int kb = wid * 3584;
        const int nss = (wid == 0) ? 112 : 80;
        for (int ks = 0; ks < nss; ++ks) {         // ss: xs[u]*ags[v]
            int ko = kb + ks * 32 + okt * 8;
            unsigned uu = (unsigned)ko / 96u;
            int v0 = ko - uu * 96;
            h8 a = rank1(s_xsh[ln][uu], (const h2*)&s_ash[ln][v0]);
            #pragma unroll
            for (int j = 0; j < 6; ++j)
                acc[j] = MFMA(a, *(const h8*)(wb + j * 16 * 7168 + ko), acc[j]);
        }
        if (wid == 1) {
            #pragma unroll 4
            for (int ks = 0; ks < 32; ++ks) {      // vv: sum_k xv[u][k]*agv[v][k]
                int ko = 6144 + ks * 32 + okt * 8;
                int kp = ko - 6144, u = kp >> 5, v0 = kp & 31;
                h2 x01 = *(const h2*)&s_xv01[ln][u * 2];
                h8 a = rank3(x01[0], x01[1], s_xv2[ln][u],
                             (const h2*)&s_avTh[ln][0][v0],
                             (const h2*)&s_avTh[ln][1][v0],
                             (const h2*)&s_avTh[ln][2][v0]);
                #pragma unroll
                for (int j = 0; j < 6; ++j)
                    acc[j] = MFMA(a, *(const h8*)(wb + j * 16 * 7168 + ko), acc[j]);
            }
        }
    } else {
        // GEMM B: hv2[(k,n)=48 x 32], K=5120 split between wid 2 (0..2559) and wid 3 (2560..5119)
        const unsigned short* b0p = wB + (size_t)ln * 5120;
        const unsigned short* b1p = wB + (size_t)(16 + ln) * 5120;
        if (wid == 2) {
            #pragma unroll 4
            for (int ks = 0; ks < 64; ++ks) {      // sv: xs[u]*agv[v][k]
                int ko = ks * 32 + okt * 8, u = ko >> 5, v0 = ko & 31;
                _Float16 x = s_xsh[ln][u];
                h8 b0 = *(const h8*)(b0p + ko), b1 = *(const h8*)(b1p + ko);
                #pragma unroll
                for (int m = 0; m < 3; ++m) {
                    h8 a = rank1(x, (const h2*)&s_avTh[ln][m][v0]);
                    acc[m * 2]     = MFMA(a, b0, acc[m * 2]);
                    acc[m * 2 + 1] = MFMA(a, b1, acc[m * 2 + 1]);
                }
            }
        }
        const int nvs = (wid == 2) ? 16 : 80;
        const int kb = (wid == 2) ? 2048 : 2560;
        for (int ks = 0; ks < nvs; ++ks) {         // vs: xv[u][k]*ags[v]
            int ko = kb + ks * 32 + okt * 8;
            int kp = ko - 2048;
            unsigned uu = (unsigned)kp / 96u;
            int v0 = kp - uu * 96;
            h2 x01 = *(const h2*)&s_xv01[ln][uu * 2];
            _Float16 x2 = s_xv2[ln][uu];
            h8 b0 = *(const h8*)(b0p + ko), b1 = *(const h8*)(b1p + ko);
            const h2* asv = (const h2*)&s_ash[ln][v0];
            #pragma unroll
            for (int m = 0; m < 3; ++m) {
                _Float16 x = (m == 0) ? x01[0] : (m == 1 ? x01[1] : x2);
                h8 a = rank1(x, asv);
                acc[m * 2]     = MFMA(a, b0, acc[m * 2]);
                acc[m * 2 + 1] = MFMA(a, b1, acc[m * 2 + 1]);
            }
        }
    }

    // ---- combine K-partials ----
    if (wid == 0) {
        #pragma unroll
        for (int j = 0; j < 6; ++j)
            #pragma unroll
            for (int r = 0; r < 4; ++r) s_hs2[okt * 4 + r][j * 16 + ln] = acc[j][r];
    } else if (wid == 2) {
        #pragma unroll
        for (int m = 0; m < 3; ++m)
            #pragma unroll
            for (int tt = 0; tt < 2; ++tt)
                #pragma unroll
                for (int r = 0; r < 4; ++r)
                    s_hv2[m * 16 + okt * 4 + r][tt * 16 + ln] = acc[m * 2 + tt][r];
    }
    __syncthreads();
    if (wid == 1) {
        #pragma unroll
        for (int j = 0; j < 6; ++j)
            #pragma unroll
            for (int r = 0; r < 4; ++r) s_hs2[okt * 4 + r][j * 16 + ln] += acc[j][r];
    } else if (wid == 3) {
        #pragma unroll
        for (int m = 0; m < 3; ++m)
            #pragma unroll
            for (int tt = 0; tt < 2; ++tt)
                #pragma unroll
                for (int r = 0; r < 4; ++r)
                    s_hv2[m * 16 + okt * 4 + r][tt * 16 + ln] += acc[m * 2 + tt][r];
    }
    __syncthreads();
    // gate transform in place: hs cols<64 -> silu, cols>=64 -> sigmoid
    for (int i = t; i < 16 * 96; i += 256) {
        int n = i / 96, w = i - n * 96;
        float h = s_hs2[n][w];
        s_hs2[n][w] = (w < 64) ? h * sigf(h) : sigf(h);
    }
    __syncthreads();
    for (int i = t; i < 48 * 32; i += 256) {
        int R = i >> 5, w2 = i & 31, n = R & 15;
        s_hv2[R][w2] *= s_hs2[n][64 + w2];
    }
    __syncthreads();
    // final irrep linear + residual
    for (int i = t; i < 16 * 64; i += 256) {
        int n = i >> 6, w = i & 63;
        float a = 0.f;
        #pragma unroll
        for (int u = 0; u < 64; ++u) a = fmaf(s_hs2[n][u], Wls[u * 64 + w], a);
        size_t o = (size_t)(n0 + n) * 160 + w;
        out[o] = nf[o] + a * 0.125f;
    }
    for (int i = t; i < 16 * 96; i += 256) {
        int n = i / 96, wk = i - n * 96, w = wk / 3, k = wk - w * 3;
        float a = 0.f;
        #pragma unroll
        for (int u = 0; u < 32; ++u) a = fmaf(s_hv2[k * 16 + n][u], Wlv[u * 32 + w], a);
        size_t o = (size_t)(n0 + n) * 160 + 64 + wk;
        out[o] = nf[o] + a * 0.17677669529663687f;
    }
}

extern "C" void kernel_launch(void* const* d_in, const int* in_sizes, int n_in,
                              void* d_out, int out_size, void* d_ws, size_t ws_size,
                              hipStream_t stream) {
    const float* nf   = (const float*)d_in[0];
    const float* ea   = (const float*)d_in[1];
    const int*   eidx = (const int*)d_in[3];
    const float* Wmss = (const float*)d_in[4];
    const float* Wmvv = (const float*)d_in[5];
    const float* Wmsv = (const float*)d_in[6];
    const float* Wmvs = (const float*)d_in[7];
    const float* Wlms = (const float*)d_in[8];
    const float* Wlmv = (const float*)d_in[9];
    const float* Wuss = (const float*)d_in[10];
    const float* Wuvv = (const float*)d_in[11];
    const float* Wusv = (const float*)d_in[12];
    const float* Wuvs = (const float*)d_in[13];
    const float* Wlus = (const float*)d_in[14];
    const float* Wluv = (const float*)d_in[15];
    float* out = (float*)d_out;

    float* agg = (float*)d_ws;                          // [NN,160]
    unsigned short* wAm = (unsigned short*)(agg + (size_t)NN * 160);
    unsigned short* wBm = wAm + 96 * 768;
    unsigned short* wAu = wBm + 32 * 768;
    unsigned short* wBu = wAu + (size_t)96 * 7168;

    const float NSM = 0.03608439182435161f;   // 1/sqrt(768)
    const float NSU = 0.011811365506297619f;  // 1/sqrt(7168)
    const float NVU = 0.013975424859373686f;  // 1/sqrt(5120)
    const float S3  = 0.57735026918962576f;   // 1/sqrt(3)

    prep_kernel<<<(96 * 768 + 255) / 256, 256, 0, stream>>>(Wmss, Wmvv, 512, 768, 96, NSM, NSM * S3, wAm, 96 * 768);
    prep_kernel<<<(32 * 768 + 255) / 256, 256, 0, stream>>>(Wmsv, Wmvs, 512, 768, 32, NSM, NSM, wBm, 32 * 768);
    prep_kernel<<<(96 * 7168 + 255) / 256, 256, 0, stream>>>(Wuss, Wuvv, 6144, 7168, 96, NSU, NSU * S3, wAu, 96 * 7168);
    prep_kernel<<<(32 * 5120 + 255) / 256, 256, 0, stream>>>(Wusv, Wuvs, 2048, 5120, 32, NVU, NVU, wBu, 32 * 5120);

    hipMemsetAsync(agg, 0, (size_t)NN * 160 * sizeof(float), stream);
    msg_kernel<<<NE / 32, 256, 0, stream>>>(nf, ea, eidx, wAm, wBm, agg);
    upd_kernel<<<NN / 16, 256, 0, stream>>>(nf, agg, wAu, wBu, Wlms, Wlmv, Wlus, Wluv, out);
}

// Round 5
// 998.241 us; speedup vs baseline: 1.1361x; 1.1361x over previous
//
#include <hip/hip_runtime.h>

#define NN 20000
#define NE 400000

typedef __attribute__((ext_vector_type(4))) float f32x4;
typedef _Float16 h2 __attribute__((ext_vector_type(2)));
typedef _Float16 h8 __attribute__((ext_vector_type(8)));

union H8 { h8 v; h2 p[4]; };

__device__ __forceinline__ float sigf(float x) { return 1.0f / (1.0f + __expf(-x)); }

__device__ __forceinline__ h8 rank1(_Float16 x, const h2 e[4]) {
    h2 xb = {x, x}; H8 f;
    #pragma unroll
    for (int j = 0; j < 4; ++j) f.p[j] = xb * e[j];
    return f.v;
}
__device__ __forceinline__ h8 rank3(_Float16 x0, _Float16 x1, _Float16 x2,
                                    const h2 e0[4], const h2 e1[4], const h2 e2[4]) {
    h2 x0b = {x0, x0}, x1b = {x1, x1}, x2b = {x2, x2}; H8 f;
    #pragma unroll
    for (int j = 0; j < 4; ++j) f.p[j] = x0b * e0[j] + x1b * e1[j] + x2b * e2[j];
    return f.v;
}
#define MFMA(a, b, c) __builtin_amdgcn_mfma_f32_16x16x32_f16(a, b, c, 0, 0, 0)

// ---------- weight prep: transpose + fp16 + fold norms: dst[w][K] = sc * src[K][w] ----------
__global__ void prep_kernel(const float* __restrict__ s1, const float* __restrict__ s2,
                            int K1, int Kt, int Nw, float sc1, float sc2,
                            unsigned short* __restrict__ dst, int total)
{
    int idx = blockIdx.x * 256 + threadIdx.x;
    if (idx >= total) return;
    int w = idx / Kt, K = idx - w * Kt;
    float v = (K < K1) ? s1[(size_t)K * Nw + w] * sc1
                       : s2[(size_t)(K - K1) * Nw + w] * sc2;
    _Float16 h = (_Float16)v;
    dst[idx] = __builtin_bit_cast(unsigned short, h);
}

// ---------- counting sort of edges by destination row ----------
__global__ void hist_kernel(const int* __restrict__ eidx, int* __restrict__ counts)
{
    int e = blockIdx.x * 256 + threadIdx.x;
    if (e < NE) atomicAdd(&counts[eidx[e]], 1);
}

__global__ void scan_kernel(int* __restrict__ data)   // in-place exclusive scan, NN elems
{
    __shared__ int buf[1024];
    __shared__ int s_carry;
    const int t = threadIdx.x;
    if (t == 0) s_carry = 0;
    __syncthreads();
    for (int base = 0; base < NN; base += 1024) {
        int idx = base + t;
        int v = (idx < NN) ? data[idx] : 0;
        buf[t] = v;
        __syncthreads();
        for (int d = 1; d < 1024; d <<= 1) {
            int x = (t >= d) ? buf[t - d] : 0;
            __syncthreads();
            buf[t] += x;
            __syncthreads();
        }
        int carry = s_carry;
        if (idx < NN) data[idx] = carry + buf[t] - v;
        __syncthreads();
        if (t == 0) s_carry = carry + buf[1023];
        __syncthreads();
    }
}

__global__ void scatter_kernel(const int* __restrict__ eidx, int* __restrict__ cursor,
                               int* __restrict__ perm)
{
    int e = blockIdx.x * 256 + threadIdx.x;
    if (e < NE) {
        int r = eidx[e];
        int p = atomicAdd(&cursor[r], 1);
        perm[p] = e;
    }
}

// ---------- msg GEMM B helper (templated so k per M-tile is a literal) ----------
template<int MB>
__device__ __forceinline__ void msg_gemmB(
    int ln, int okt,
    const _Float16 (*s_xsh)[68], const _Float16 (*s_xv01)[66], const _Float16 (*s_xv2)[34],
    const _Float16 (*s_esh)[8], const _Float16 (*s_evTh)[7][8],
    const unsigned short* __restrict__ wB, f32x4 acc[6])
{
    const int k0 = (MB + 0) >> 1, k1 = (MB + 1) >> 1, k2 = (MB + 2) >> 1;
    const int ea = (((MB + 0) & 1) << 4) + ln;
    const int eb = (((MB + 1) & 1) << 4) + ln;
    const int ec = (((MB + 2) & 1) << 4) + ln;
    const unsigned short* b0p = wB + (size_t)ln * 768;
    const unsigned short* b1p = wB + (size_t)(16 + ln) * 768;

    h2 sv0[4], sv1[4], sv2[4], es0[4], es1[4], es2[4];
    #pragma unroll
    for (int j = 0; j < 4; ++j) {
        sv0[j] = ((const h2*)s_evTh[ea][k0])[j];
        sv1[j] = ((const h2*)s_evTh[eb][k1])[j];
        sv2[j] = ((const h2*)s_evTh[ec][k2])[j];
        es0[j] = ((const h2*)s_esh[ea])[j];
        es1[j] = ((const h2*)s_esh[eb])[j];
        es2[j] = ((const h2*)s_esh[ec])[j];
    }
    // sv region: z = xs[u]*ev[v][k]
    #pragma unroll 4
    for (int ks = 0; ks < 16; ++ks) {
        int ko = ks * 32 + okt * 8, u = ks * 4 + okt;
        h8 b0 = *(const h8*)(b0p + ko), b1 = *(const h8*)(b1p + ko);
        h8 a0 = rank1(s_xsh[ea][u], sv0);
        h8 a1 = rank1(s_xsh[eb][u], sv1);
        h8 a2 = rank1(s_xsh[ec][u], sv2);
        acc[0] = MFMA(a0, b0, acc[0]); acc[1] = MFMA(a0, b1, acc[1]);
        acc[2] = MFMA(a1, b0, acc[2]); acc[3] = MFMA(a1, b1, acc[3]);
        acc[4] = MFMA(a2, b0, acc[4]); acc[5] = MFMA(a2, b1, acc[5]);
    }
    // vs region: z = xv[u][k]*es[v]
    #pragma unroll 4
    for (int ks = 0; ks < 8; ++ks) {
        int ko = 512 + ks * 32 + okt * 8, u = ks * 4 + okt;
        h8 b0 = *(const h8*)(b0p + ko), b1 = *(const h8*)(b1p + ko);
        _Float16 xa = (k0 == 0) ? s_xv01[ea][u * 2] : (k0 == 1 ? s_xv01[ea][u * 2 + 1] : s_xv2[ea][u]);
        _Float16 xb = (k1 == 0) ? s_xv01[eb][u * 2] : (k1 == 1 ? s_xv01[eb][u * 2 + 1] : s_xv2[eb][u]);
        _Float16 xc = (k2 == 0) ? s_xv01[ec][u * 2] : (k2 == 1 ? s_xv01[ec][u * 2 + 1] : s_xv2[ec][u]);
        h8 a0 = rank1(xa, es0);
        h8 a1 = rank1(xb, es1);
        h8 a2 = rank1(xc, es2);
        acc[0] = MFMA(a0, b0, acc[0]); acc[1] = MFMA(a0, b1, acc[1]);
        acc[2] = MFMA(a1, b0, acc[2]); acc[3] = MFMA(a1, b1, acc[3]);
        acc[4] = MFMA(a2, b0, acc[4]); acc[5] = MFMA(a2, b1, acc[5]);
    }
}

// =============== message kernel: 32 sorted edges/block, segmented-reduce scatter ===============
__global__ __launch_bounds__(256, 5)
void msg_kernel(const float* __restrict__ nf, const float* __restrict__ ea,
                const int* __restrict__ eidx, const int* __restrict__ perm,
                const unsigned short* __restrict__ wA,   // [96][768] fp16, norms folded
                const unsigned short* __restrict__ wB,   // [32][768] fp16, norms folded
                float* __restrict__ agg)
{
    const int e0 = blockIdx.x * 32;
    const int t = threadIdx.x;
    const int wid = t >> 6, lane = t & 63, ln = lane & 15, okt = lane >> 4;

    // overlay: fp16 staging (14848 B, dead after GEMM) ∪ s_msg (32*164*4 = 20992 B)
    __shared__ __align__(16) char smem[20992];
    _Float16 (*s_xsh)[68]    = (_Float16(*)[68])(smem);
    _Float16 (*s_xv01)[66]   = (_Float16(*)[66])(smem + 4352);
    _Float16 (*s_xv2)[34]    = (_Float16(*)[34])(smem + 8576);
    _Float16 (*s_esh)[8]     = (_Float16(*)[8])(smem + 10752);
    _Float16 (*s_evTh)[7][8] = (_Float16(*)[7][8])(smem + 11264);
    float (*s_msg)[164]      = (float(*)[164])(smem);

    __shared__ float s_gate[32][33];
    __shared__ int s_row[32], s_col[32], s_pe[32];

    if (t < 32) {
        int p = perm[e0 + t];
        s_pe[t] = p;
        s_row[t] = eidx[p];
        s_col[t] = eidx[NE + p];
    }
    __syncthreads();
    for (int i = t; i < 32 * 32; i += 256) {
        int e = i >> 5, c = i & 31;
        float v = ea[(size_t)s_pe[e] * 32 + c];
        if (c < 8) s_esh[e][c] = (_Float16)v;
        else { int d = c - 8; s_evTh[e][d % 3][d / 3] = (_Float16)v; }
    }
    for (int i = t; i < 32 * 40; i += 256) {
        int e = i / 40, q = i - e * 40;
        f32x4 f4 = *((const f32x4*)nf + (size_t)s_col[e] * 40 + q);
        if (q < 16) {
            #pragma unroll
            for (int j = 0; j < 4; ++j) s_xsh[e][q * 4 + j] = (_Float16)f4[j];
        } else {
            #pragma unroll
            for (int j = 0; j < 4; ++j) {
                int d = (q - 16) * 4 + j, u = d / 3, k = d - u * 3;
                if (k < 2) s_xv01[e][u * 2 + k] = (_Float16)f4[j];
                else       s_xv2[e][u] = (_Float16)f4[j];
            }
        }
    }
    __syncthreads();

    f32x4 acc[6] = {};

    if (wid < 2) {
        // GEMM A: hs[32x96]; this wave: edges wid*16..+15, all 6 N-tiles
        const int e = wid * 16 + ln;
        const unsigned short* wb = wA + (size_t)ln * 768;
        h2 esv[4];
        #pragma unroll
        for (int j = 0; j < 4; ++j) esv[j] = ((const h2*)s_esh[e])[j];
        #pragma unroll 4
        for (int ks = 0; ks < 16; ++ks) {          // ss: xs[u]*es[v]
            int ko = ks * 32 + okt * 8, u = ks * 4 + okt;
            h8 a = rank1(s_xsh[e][u], esv);
            #pragma unroll
            for (int j = 0; j < 6; ++j)
                acc[j] = MFMA(a, *(const h8*)(wb + j * 16 * 768 + ko), acc[j]);
        }
        h2 e0v[4], e1v[4], e2v[4];
        #pragma unroll
        for (int j = 0; j < 4; ++j) {
            e0v[j] = ((const h2*)s_evTh[e][0])[j];
            e1v[j] = ((const h2*)s_evTh[e][1])[j];
            e2v[j] = ((const h2*)s_evTh[e][2])[j];
        }
        #pragma unroll 4
        for (int ks = 0; ks < 8; ++ks) {           // dd: sum_k xv[u][k]*ev[v][k]
            int ko = 512 + ks * 32 + okt * 8, u = ks * 4 + okt;
            h2 x01 = *(const h2*)&s_xv01[e][u * 2];
            h8 a = rank3(x01[0], x01[1], s_xv2[e][u], e0v, e1v, e2v);
            #pragma unroll
            for (int j = 0; j < 6; ++j)
                acc[j] = MFMA(a, *(const h8*)(wb + j * 16 * 768 + ko), acc[j]);
        }
    } else if (wid == 2) {
        msg_gemmB<0>(ln, okt, s_xsh, s_xv01, s_xv2, s_esh, s_evTh, wB, acc);
    } else {
        msg_gemmB<3>(ln, okt, s_xsh, s_xv01, s_xv2, s_esh, s_evTh, wB, acc);
    }

    __syncthreads();   // all GEMM reads of staging done -> s_msg may overwrite

    // ---- epilogue: gate, stage in LDS ----
    if (wid < 2) {
        #pragma unroll
        for (int j = 0; j < 6; ++j)
            #pragma unroll
            for (int r = 0; r < 4; ++r) {
                int e = wid * 16 + okt * 4 + r;
                float h = acc[j][r];
                if (j < 4) s_msg[e][j * 16 + ln] = h * sigf(h);
                else       s_gate[e][(j - 4) * 16 + ln] = sigf(h);
            }
    }
    __syncthreads();
    if (wid >= 2) {
        int mb = (wid - 2) * 3;
        #pragma unroll
        for (int m = 0; m < 3; ++m) {
            int mm = mb + m, k = mm >> 1;
            #pragma unroll
            for (int tt = 0; tt < 2; ++tt)
                #pragma unroll
                for (int r = 0; r < 4; ++r) {
                    int e = ((mm & 1) << 4) + okt * 4 + r;
                    int w2 = tt * 16 + ln;
                    s_msg[e][64 + w2 * 3 + k] = acc[m * 2 + tt][r] * s_gate[e][w2];
                }
        }
    }
    __syncthreads();

    // ---- segmented reduce over sorted rows: ~2-4 distinct rows/block ----
    if (t < 160) {
        int cur = s_row[0];
        float a = s_msg[0][t];
        for (int e = 1; e < 32; ++e) {
            int r = s_row[e];          // uniform across threads -> no divergence
            float v = s_msg[e][t];
            if (r != cur) {
                atomicAdd(agg + (size_t)cur * 160 + t, a);
                cur = r; a = v;
            } else a += v;
        }
        atomicAdd(agg + (size_t)cur * 160 + t, a);
    }
}

// =============== update kernel: 16 nodes/block, folded agglin, K-split waves ===============
__global__ __launch_bounds__(256, 4)
void upd_kernel(const float* __restrict__ nf, const float* __restrict__ agg,
                const unsigned short* __restrict__ wA,   // [96][7168] fp16
                const unsigned short* __restrict__ wB,   // [32][5120] fp16
                const float* __restrict__ Wlms, const float* __restrict__ Wlmv,
                const float* __restrict__ Wls, const float* __restrict__ Wlv,
                float* __restrict__ out)
{
    const int n0 = blockIdx.x * 16;
    const int t = threadIdx.x;
    const int wid = t >> 6, lane = t & 63, ln = lane & 15, okt = lane >> 4;

    __shared__ __align__(16) _Float16 s_xsh[16][68];
    __shared__ __align__(16) _Float16 s_xv01[16][66];
    __shared__ __align__(16) _Float16 s_xv2[16][34];
    __shared__ __align__(16) _Float16 s_ash[16][104];     // ags fp16
    __shared__ __align__(16) _Float16 s_avTh[16][3][40];  // agv^T fp16
    __shared__ float s_hs2[16][100];
    __shared__ float s_hv2[48][34];                       // rows (k*16+n)
    __shared__ float s_ag[16][160];

    for (int i = t; i < 16 * 160; i += 256)
        ((float*)s_ag)[i] = agg[(size_t)n0 * 160 + i];
    for (int i = t; i < 16 * 40; i += 256) {
        int n = i / 40, q = i - n * 40;
        f32x4 f4 = *((const f32x4*)nf + (size_t)(n0 + n) * 40 + q);
        if (q < 16) {
            #pragma unroll
            for (int j = 0; j < 4; ++j) s_xsh[n][q * 4 + j] = (_Float16)f4[j];
        } else {
            #pragma unroll
            for (int j = 0; j < 4; ++j) {
                int d = (q - 16) * 4 + j, u = d / 3, k = d - u * 3;
                if (k < 2) s_xv01[n][u * 2 + k] = (_Float16)f4[j];
                else       s_xv2[n][u] = (_Float16)f4[j];
            }
        }
    }
    __syncthreads();
    // folded agglin (linear commuted past segment_sum)
    #pragma unroll
    for (int r = 0; r < 6; ++r) {
        int o = t + r * 256;
        int n = o / 96, q = o - n * 96;
        float a = 0.f;
        #pragma unroll
        for (int u = 0; u < 64; ++u) a = fmaf(s_ag[n][u], Wlms[u * 96 + q], a);
        s_ash[n][q] = (_Float16)(a * 0.125f);
    }
    #pragma unroll
    for (int r = 0; r < 6; ++r) {
        int o = t + r * 256;
        int n = o / 96, q = o - n * 96, k = q >> 5, v = q & 31;
        float a = 0.f;
        #pragma unroll
        for (int u = 0; u < 32; ++u) a = fmaf(s_ag[n][64 + u * 3 + k], Wlmv[u * 32 + v], a);
        s_avTh[n][k][v] = (_Float16)(a * 0.17677669529663687f);
    }
    __syncthreads();

    f32x4 acc[6] = {};

    if (wid < 2) {
        // GEMM A: hs2[16x96], K=7168 split between wid 0 (0..3583) and wid 1 (3584..7167)
        const unsigned short* wb = wA + (size_t)ln * 7168;
        const int kb = wid * 3584;
        const int nss = (wid == 0) ? 112 : 80;
        for (int ks = 0; ks < nss; ++ks) {         // ss: xs[u]*ags[v]
            int ko = kb + ks * 32 + okt * 8;
            unsigned uu = (unsigned)ko / 96u;
            int v0 = ko - uu * 96;
            h8 a = rank1(s_xsh[ln][uu], (const h2*)&s_ash[ln][v0]);
            #pragma unroll
            for (int j = 0; j < 6; ++j)
                acc[j] = MFMA(a, *(const h8*)(wb + j * 16 * 7168 + ko), acc[j]);
        }
        if (wid == 1) {
            #pragma unroll 4
            for (int ks = 0; ks < 32; ++ks) {      // vv: sum_k xv[u][k]*agv[v][k]
                int ko = 6144 + ks * 32 + okt * 8;
                int kp = ko - 6144, u = kp >> 5, v0 = kp & 31;
                h2 x01 = *(const h2*)&s_xv01[ln][u * 2];
                h8 a = rank3(x01[0], x01[1], s_xv2[ln][u],
                             (const h2*)&s_avTh[ln][0][v0],
                             (const h2*)&s_avTh[ln][1][v0],
                             (const h2*)&s_avTh[ln][2][v0]);
                #pragma unroll
                for (int j = 0; j < 6; ++j)
                    acc[j] = MFMA(a, *(const h8*)(wb + j * 16 * 7168 + ko), acc[j]);
            }
        }
    } else {
        // GEMM B: hv2[(k,n)=48 x 32], K=5120 split between wid 2 (0..2559) and wid 3 (2560..5119)
        const unsigned short* b0p = wB + (size_t)ln * 5120;
        const unsigned short* b1p = wB + (size_t)(16 + ln) * 5120;
        if (wid == 2) {
            #pragma unroll 4
            for (int ks = 0; ks < 64; ++ks) {      // sv: xs[u]*agv[v][k]
                int ko = ks * 32 + okt * 8, u = ko >> 5, v0 = ko & 31;
                _Float16 x = s_xsh[ln][u];
                h8 b0 = *(const h8*)(b0p + ko), b1 = *(const h8*)(b1p + ko);
                #pragma unroll
                for (int m = 0; m < 3; ++m) {
                    h8 a = rank1(x, (const h2*)&s_avTh[ln][m][v0]);
                    acc[m * 2]     = MFMA(a, b0, acc[m * 2]);
                    acc[m * 2 + 1] = MFMA(a, b1, acc[m * 2 + 1]);
                }
            }
        }
        const int nvs = (wid == 2) ? 16 : 80;
        const int kb = (wid == 2) ? 2048 : 2560;
        for (int ks = 0; ks < nvs; ++ks) {         // vs: xv[u][k]*ags[v]
            int ko = kb + ks * 32 + okt * 8;
            int kp = ko - 2048;
            unsigned uu = (unsigned)kp / 96u;
            int v0 = kp - uu * 96;
            h2 x01 = *(const h2*)&s_xv01[ln][uu * 2];
            _Float16 x2 = s_xv2[ln][uu];
            h8 b0 = *(const h8*)(b0p + ko), b1 = *(const h8*)(b1p + ko);
            const h2* asv = (const h2*)&s_ash[ln][v0];
            #pragma unroll
            for (int m = 0; m < 3; ++m) {
                _Float16 x = (m == 0) ? x01[0] : (m == 1 ? x01[1] : x2);
                h8 a = rank1(x, asv);
                acc[m * 2]     = MFMA(a, b0, acc[m * 2]);
                acc[m * 2 + 1] = MFMA(a, b1, acc[m * 2 + 1]);
            }
        }
    }

    // ---- combine K-partials ----
    if (wid == 0) {
        #pragma unroll
        for (int j = 0; j < 6; ++j)
            #pragma unroll
            for (int r = 0; r < 4; ++r) s_hs2[okt * 4 + r][j * 16 + ln] = acc[j][r];
    } else if (wid == 2) {
        #pragma unroll
        for (int m = 0; m < 3; ++m)
            #pragma unroll
            for (int tt = 0; tt < 2; ++tt)
                #pragma unroll
                for (int r = 0; r < 4; ++r)
                    s_hv2[m * 16 + okt * 4 + r][tt * 16 + ln] = acc[m * 2 + tt][r];
    }
    __syncthreads();
    if (wid == 1) {
        #pragma unroll
        for (int j = 0; j < 6; ++j)
            #pragma unroll
            for (int r = 0; r < 4; ++r) s_hs2[okt * 4 + r][j * 16 + ln] += acc[j][r];
    } else if (wid == 3) {
        #pragma unroll
        for (int m = 0; m < 3; ++m)
            #pragma unroll
            for (int tt = 0; tt < 2; ++tt)
                #pragma unroll
                for (int r = 0; r < 4; ++r)
                    s_hv2[m * 16 + okt * 4 + r][tt * 16 + ln] += acc[m * 2 + tt][r];
    }
    __syncthreads();
    // gate transform in place: hs cols<64 -> silu, cols>=64 -> sigmoid
    for (int i = t; i < 16 * 96; i += 256) {
        int n = i / 96, w = i - n * 96;
        float h = s_hs2[n][w];
        s_hs2[n][w] = (w < 64) ? h * sigf(h) : sigf(h);
    }
    __syncthreads();
    for (int i = t; i < 48 * 32; i += 256) {
        int R = i >> 5, w2 = i & 31, n = R & 15;
        s_hv2[R][w2] *= s_hs2[n][64 + w2];
    }
    __syncthreads();
    // final irrep linear + residual
    for (int i = t; i < 16 * 64; i += 256) {
        int n = i >> 6, w = i & 63;
        float a = 0.f;
        #pragma unroll
        for (int u = 0; u < 64; ++u) a = fmaf(s_hs2[n][u], Wls[u * 64 + w], a);
        size_t o = (size_t)(n0 + n) * 160 + w;
        out[o] = nf[o] + a * 0.125f;
    }
    for (int i = t; i < 16 * 96; i += 256) {
        int n = i / 96, wk = i - n * 96, w = wk / 3, k = wk - w * 3;
        float a = 0.f;
        #pragma unroll
        for (int u = 0; u < 32; ++u) a = fmaf(s_hv2[k * 16 + n][u], Wlv[u * 32 + w], a);
        size_t o = (size_t)(n0 + n) * 160 + 64 + wk;
        out[o] = nf[o] + a * 0.17677669529663687f;
    }
}

extern "C" void kernel_launch(void* const* d_in, const int* in_sizes, int n_in,
                              void* d_out, int out_size, void* d_ws, size_t ws_size,
                              hipStream_t stream) {
    const float* nf   = (const float*)d_in[0];
    const float* ea   = (const float*)d_in[1];
    const int*   eidx = (const int*)d_in[3];
    const float* Wmss = (const float*)d_in[4];
    const float* Wmvv = (const float*)d_in[5];
    const float* Wmsv = (const float*)d_in[6];
    const float* Wmvs = (const float*)d_in[7];
    const float* Wlms = (const float*)d_in[8];
    const float* Wlmv = (const float*)d_in[9];
    const float* Wuss = (const float*)d_in[10];
    const float* Wuvv = (const float*)d_in[11];
    const float* Wusv = (const float*)d_in[12];
    const float* Wuvs = (const float*)d_in[13];
    const float* Wlus = (const float*)d_in[14];
    const float* Wluv = (const float*)d_in[15];
    float* out = (float*)d_out;

    float* agg = (float*)d_ws;                          // [NN,160]
    unsigned short* wAm = (unsigned short*)(agg + (size_t)NN * 160);
    unsigned short* wBm = wAm + 96 * 768;
    unsigned short* wAu = wBm + 32 * 768;
    unsigned short* wBu = wAu + (size_t)96 * 7168;
    int* counts = (int*)(wBu + (size_t)32 * 5120);      // [NN] -> becomes cursor
    int* perm   = counts + NN;                          // [NE]

    const float NSM = 0.03608439182435161f;   // 1/sqrt(768)
    const float NSU = 0.011811365506297619f;  // 1/sqrt(7168)
    const float NVU = 0.013975424859373686f;  // 1/sqrt(5120)
    const float S3  = 0.57735026918962576f;   // 1/sqrt(3)

    hipMemsetAsync(agg, 0, (size_t)NN * 160 * sizeof(float), stream);
    hipMemsetAsync(counts, 0, (size_t)NN * sizeof(int), stream);

    prep_kernel<<<(96 * 768 + 255) / 256, 256, 0, stream>>>(Wmss, Wmvv, 512, 768, 96, NSM, NSM * S3, wAm, 96 * 768);
    prep_kernel<<<(32 * 768 + 255) / 256, 256, 0, stream>>>(Wmsv, Wmvs, 512, 768, 32, NSM, NSM, wBm, 32 * 768);
    prep_kernel<<<(96 * 7168 + 255) / 256, 256, 0, stream>>>(Wuss, Wuvv, 6144, 7168, 96, NSU, NSU * S3, wAu, 96 * 7168);
    prep_kernel<<<(32 * 5120 + 255) / 256, 256, 0, stream>>>(Wusv, Wuvs, 2048, 5120, 32, NVU, NVU, wBu, 32 * 5120);

    hist_kernel<<<(NE + 255) / 256, 256, 0, stream>>>(eidx, counts);
    scan_kernel<<<1, 1024, 0, stream>>>(counts);
    scatter_kernel<<<(NE + 255) / 256, 256, 0, stream>>>(eidx, counts, perm);

    msg_kernel<<<NE / 32, 256, 0, stream>>>(nf, ea, eidx, perm, wAm, wBm, agg);
    upd_kernel<<<NN / 16, 256, 0, stream>>>(nf, agg, wAu, wBu, Wlms, Wlmv, Wlus, Wluv, out);
}

// Round 6
// 574.857 us; speedup vs baseline: 1.9729x; 1.7365x over previous
//
#include <hip/hip_runtime.h>

#define NN 20000
#define NE 400000

typedef __attribute__((ext_vector_type(4))) float f32x4;
typedef _Float16 h2 __attribute__((ext_vector_type(2)));
typedef _Float16 h8 __attribute__((ext_vector_type(8)));

union H8 { h8 v; h2 p[4]; };

__device__ __forceinline__ float sigf(float x) { return 1.0f / (1.0f + __expf(-x)); }

__device__ __forceinline__ h8 rank1(_Float16 x, const h2 e[4]) {
    h2 xb = {x, x}; H8 f;
    #pragma unroll
    for (int j = 0; j < 4; ++j) f.p[j] = xb * e[j];
    return f.v;
}
__device__ __forceinline__ h8 rank3(_Float16 x0, _Float16 x1, _Float16 x2,
                                    const h2 e0[4], const h2 e1[4], const h2 e2[4]) {
    h2 x0b = {x0, x0}, x1b = {x1, x1}, x2b = {x2, x2}; H8 f;
    #pragma unroll
    for (int j = 0; j < 4; ++j) f.p[j] = x0b * e0[j] + x1b * e1[j] + x2b * e2[j];
    return f.v;
}
#define MFMA(a, b, c) __builtin_amdgcn_mfma_f32_16x16x32_f16(a, b, c, 0, 0, 0)

// ---------- weight prep: transpose + fp16 + fold norms: dst[w][K] = sc * src[K][w] ----------
__global__ void prep_kernel(const float* __restrict__ s1, const float* __restrict__ s2,
                            int K1, int Kt, int Nw, float sc1, float sc2,
                            unsigned short* __restrict__ dst, int total)
{
    int idx = blockIdx.x * 256 + threadIdx.x;
    if (idx >= total) return;
    int w = idx / Kt, K = idx - w * Kt;
    float v = (K < K1) ? s1[(size_t)K * Nw + w] * sc1
                       : s2[(size_t)(K - K1) * Nw + w] * sc2;
    _Float16 h = (_Float16)v;
    dst[idx] = __builtin_bit_cast(unsigned short, h);
}

// ---------- counting sort of edges by destination row ----------
__global__ void hist_kernel(const int* __restrict__ eidx, int* __restrict__ counts)
{
    int e = blockIdx.x * 256 + threadIdx.x;
    if (e < NE) atomicAdd(&counts[eidx[e]], 1);
}

__global__ __launch_bounds__(1024)
void scan_kernel(int* __restrict__ data)   // in-place exclusive scan, NN elems
{
    __shared__ int wsum[16];
    __shared__ int s_carry;
    const int t = threadIdx.x, lane = t & 63, wv = t >> 6;
    if (t == 0) s_carry = 0;
    __syncthreads();
    for (int base = 0; base < NN; base += 1024) {
        int carry = s_carry;
        int idx = base + t;
        int v = (idx < NN) ? data[idx] : 0;
        int s = v;
        #pragma unroll
        for (int d = 1; d < 64; d <<= 1) {
            int x = __shfl_up(s, d, 64);
            if (lane >= d) s += x;
        }
        if (lane == 63) wsum[wv] = s;
        __syncthreads();
        if (t < 16) {
            int ws = wsum[t];
            #pragma unroll
            for (int d = 1; d < 16; d <<= 1) {
                int x = __shfl_up(ws, d, 64);
                if (t >= d) ws += x;
            }
            wsum[t] = ws;
        }
        __syncthreads();
        if (idx < NN) data[idx] = carry + (wv ? wsum[wv - 1] : 0) + s - v;
        if (t == 0) s_carry = carry + wsum[15];
        __syncthreads();
    }
}

__global__ void scatter_kernel(const int* __restrict__ eidx, int* __restrict__ cursor,
                               int* __restrict__ perm)
{
    int e = blockIdx.x * 256 + threadIdx.x;
    if (e < NE) {
        int r = eidx[e];
        int p = atomicAdd(&cursor[r], 1);
        perm[p] = e;
    }
}

// ---------- msg GEMM B: M-tiles MB..MB+5 of hv[(k,e)=192 x 32], both N-tiles ----------
template<int MB>
__device__ __forceinline__ void msg_gemmB(
    int ln, int okt,
    const _Float16 (*s_xsh)[68], const _Float16 (*s_xv01)[66], const _Float16 (*s_xv2)[34],
    const _Float16 (*s_esh)[8], const _Float16 (*s_evTh)[3][8],
    const unsigned short* __restrict__ wB, f32x4* acc)
{
    const unsigned short* b0p = wB + (size_t)ln * 768;
    const unsigned short* b1p = wB + (size_t)(16 + ln) * 768;

    h2 vv[6][4];
    #pragma unroll
    for (int m = 0; m < 6; ++m) {
        const int k = (MB + m) >> 2, e = (((MB + m) & 3) << 4) + ln;
        #pragma unroll
        for (int j = 0; j < 4; ++j) vv[m][j] = ((const h2*)s_evTh[e][k])[j];
    }
    #pragma unroll 4
    for (int ks = 0; ks < 16; ++ks) {          // sv region: z = xs[u]*ev[v][k]
        const int ko = ks * 32 + okt * 8, u = ks * 4 + okt;
        h8 b0 = *(const h8*)(b0p + ko), b1 = *(const h8*)(b1p + ko);
        #pragma unroll
        for (int m = 0; m < 6; ++m) {
            const int e = (((MB + m) & 3) << 4) + ln;
            h8 a = rank1(s_xsh[e][u], vv[m]);
            acc[m * 2]     = MFMA(a, b0, acc[m * 2]);
            acc[m * 2 + 1] = MFMA(a, b1, acc[m * 2 + 1]);
        }
    }
    h2 ee[6][4];
    #pragma unroll
    for (int m = 0; m < 6; ++m) {
        const int e = (((MB + m) & 3) << 4) + ln;
        #pragma unroll
        for (int j = 0; j < 4; ++j) ee[m][j] = ((const h2*)s_esh[e])[j];
    }
    #pragma unroll 4
    for (int ks = 0; ks < 8; ++ks) {           // vs region: z = xv[u][k]*es[v]
        const int ko = 512 + ks * 32 + okt * 8, u = ks * 4 + okt;
        h8 b0 = *(const h8*)(b0p + ko), b1 = *(const h8*)(b1p + ko);
        #pragma unroll
        for (int m = 0; m < 6; ++m) {
            const int k = (MB + m) >> 2, e = (((MB + m) & 3) << 4) + ln;
            _Float16 x = (k < 2) ? s_xv01[e][u * 2 + k] : s_xv2[e][u];
            h8 a = rank1(x, ee[m]);
            acc[m * 2]     = MFMA(a, b0, acc[m * 2]);
            acc[m * 2 + 1] = MFMA(a, b1, acc[m * 2 + 1]);
        }
    }
}

// =============== message kernel: 64 sorted edges/block, full-M waves, N-split ===============
__global__ __launch_bounds__(256, 3)
void msg_kernel(const float* __restrict__ nf, const float* __restrict__ ea,
                const int* __restrict__ eidx, const int* __restrict__ perm,
                const unsigned short* __restrict__ wA,   // [96][768] fp16, norms folded
                const unsigned short* __restrict__ wB,   // [32][768] fp16, norms folded
                float* __restrict__ agg)
{
    const int e0 = blockIdx.x * 64;
    const int t = threadIdx.x;
    const int wid = t >> 6, lane = t & 63, ln = lane & 15, okt = lane >> 4;

    // overlay: fp16 staging (25600 B, dead after GEMM) ∪ s_msg (64*161*4 = 41216 B)
    __shared__ __align__(16) char smem[41216];
    _Float16 (*s_xsh)[68]    = (_Float16(*)[68])(smem);
    _Float16 (*s_xv01)[66]   = (_Float16(*)[66])(smem + 8704);
    _Float16 (*s_xv2)[34]    = (_Float16(*)[34])(smem + 17152);
    _Float16 (*s_esh)[8]     = (_Float16(*)[8])(smem + 21504);
    _Float16 (*s_evTh)[3][8] = (_Float16(*)[3][8])(smem + 22528);
    float (*s_msg)[161]      = (float(*)[161])(smem);

    __shared__ float s_gate[64][33];
    __shared__ int s_row[64], s_col[64], s_pe[64];

    if (t < 64) {
        int p = perm[e0 + t];
        s_pe[t] = p;
        s_row[t] = eidx[p];
        s_col[t] = eidx[NE + p];
    }
    __syncthreads();
    for (int i = t; i < 64 * 32; i += 256) {
        int e = i >> 5, c = i & 31;
        float v = ea[(size_t)s_pe[e] * 32 + c];
        if (c < 8) s_esh[e][c] = (_Float16)v;
        else { int d = c - 8; s_evTh[e][d % 3][d / 3] = (_Float16)v; }
    }
    for (int i = t; i < 64 * 40; i += 256) {
        int e = i / 40, q = i - e * 40;
        f32x4 f4 = *((const f32x4*)nf + (size_t)s_col[e] * 40 + q);
        if (q < 16) {
            #pragma unroll
            for (int j = 0; j < 4; ++j) s_xsh[e][q * 4 + j] = (_Float16)f4[j];
        } else {
            #pragma unroll
            for (int j = 0; j < 4; ++j) {
                int d = (q - 16) * 4 + j, u = d / 3, k = d - u * 3;
                if (k < 2) s_xv01[e][u * 2 + k] = (_Float16)f4[j];
                else       s_xv2[e][u] = (_Float16)f4[j];
            }
        }
    }
    __syncthreads();

    f32x4 acc[12] = {};

    if (wid < 2) {
        // GEMM A: hs[64 x 96]; wave covers all 4 M-tiles, N-tiles wid*3..wid*3+2
        const unsigned short* wb = wA + (size_t)(wid * 48 + ln) * 768;
        h2 esv[4][4];
        #pragma unroll
        for (int m = 0; m < 4; ++m)
            #pragma unroll
            for (int j = 0; j < 4; ++j) esv[m][j] = ((const h2*)s_esh[m * 16 + ln])[j];
        #pragma unroll 4
        for (int ks = 0; ks < 16; ++ks) {          // ss: xs[u]*es[v]
            const int ko = ks * 32 + okt * 8, u = ks * 4 + okt;
            h8 b0 = *(const h8*)(wb + ko);
            h8 b1 = *(const h8*)(wb + 16 * 768 + ko);
            h8 b2 = *(const h8*)(wb + 32 * 768 + ko);
            #pragma unroll
            for (int m = 0; m < 4; ++m) {
                h8 a = rank1(s_xsh[m * 16 + ln][u], esv[m]);
                acc[m * 3 + 0] = MFMA(a, b0, acc[m * 3 + 0]);
                acc[m * 3 + 1] = MFMA(a, b1, acc[m * 3 + 1]);
                acc[m * 3 + 2] = MFMA(a, b2, acc[m * 3 + 2]);
            }
        }
        h2 ev0[4][4], ev1[4][4], ev2[4][4];
        #pragma unroll
        for (int m = 0; m < 4; ++m)
            #pragma unroll
            for (int j = 0; j < 4; ++j) {
                ev0[m][j] = ((const h2*)s_evTh[m * 16 + ln][0])[j];
                ev1[m][j] = ((const h2*)s_evTh[m * 16 + ln][1])[j];
                ev2[m][j] = ((const h2*)s_evTh[m * 16 + ln][2])[j];
            }
        #pragma unroll 4
        for (int ks = 0; ks < 8; ++ks) {           // dd: sum_k xv[u][k]*ev[v][k]
            const int ko = 512 + ks * 32 + okt * 8, u = ks * 4 + okt;
            h8 b0 = *(const h8*)(wb + ko);
            h8 b1 = *(const h8*)(wb + 16 * 768 + ko);
            h8 b2 = *(const h8*)(wb + 32 * 768 + ko);
            #pragma unroll
            for (int m = 0; m < 4; ++m) {
                h2 x01 = *(const h2*)&s_xv01[m * 16 + ln][u * 2];
                h8 a = rank3(x01[0], x01[1], s_xv2[m * 16 + ln][u], ev0[m], ev1[m], ev2[m]);
                acc[m * 3 + 0] = MFMA(a, b0, acc[m * 3 + 0]);
                acc[m * 3 + 1] = MFMA(a, b1, acc[m * 3 + 1]);
                acc[m * 3 + 2] = MFMA(a, b2, acc[m * 3 + 2]);
            }
        }
    } else if (wid == 2) {
        msg_gemmB<0>(ln, okt, s_xsh, s_xv01, s_xv2, s_esh, s_evTh, wB, acc);
    } else {
        msg_gemmB<6>(ln, okt, s_xsh, s_xv01, s_xv2, s_esh, s_evTh, wB, acc);
    }

    __syncthreads();   // all GEMM reads of staging done -> s_msg may overwrite

    // ---- epilogue phase 1: scalars + gates ----
    if (wid < 2) {
        #pragma unroll
        for (int m = 0; m < 4; ++m)
            #pragma unroll
            for (int j = 0; j < 3; ++j)
                #pragma unroll
                for (int r = 0; r < 4; ++r) {
                    int e = m * 16 + okt * 4 + r;
                    int w = wid * 48 + j * 16 + ln;
                    float h = acc[m * 3 + j][r];
                    if (w < 64) s_msg[e][w] = h * sigf(h);
                    else        s_gate[e][w - 64] = sigf(h);
                }
    }
    __syncthreads();
    // ---- epilogue phase 2: gated vectors ----
    if (wid >= 2) {
        const int mb = (wid - 2) * 6;
        #pragma unroll
        for (int m = 0; m < 6; ++m) {
            int mm = mb + m, k = mm >> 2;
            #pragma unroll
            for (int tt = 0; tt < 2; ++tt)
                #pragma unroll
                for (int r = 0; r < 4; ++r) {
                    int e = ((mm & 3) << 4) + okt * 4 + r;
                    int w2 = tt * 16 + ln;
                    s_msg[e][64 + w2 * 3 + k] = acc[m * 2 + tt][r] * s_gate[e][w2];
                }
        }
    }
    __syncthreads();

    // ---- segmented reduce over sorted rows ----
    if (t < 160) {
        int cur = s_row[0];
        float a = s_msg[0][t];
        for (int e = 1; e < 64; ++e) {
            int r = s_row[e];          // uniform across threads
            float v = s_msg[e][t];
            if (r != cur) {
                atomicAdd(agg + (size_t)cur * 160 + t, a);
                cur = r; a = v;
            } else a += v;
        }
        atomicAdd(agg + (size_t)cur * 160 + t, a);
    }
}

// =============== update kernel: 32 nodes/block, folded agglin, full-M waves, N-split ===============
__global__ __launch_bounds__(256, 2)
void upd_kernel(const float* __restrict__ nf, const float* __restrict__ agg,
                const unsigned short* __restrict__ wA,   // [96][7168] fp16
                const unsigned short* __restrict__ wB,   // [32][5120] fp16
                const float* __restrict__ Wlms, const float* __restrict__ Wlmv,
                const float* __restrict__ Wls, const float* __restrict__ Wlv,
                float* __restrict__ out)
{
    const int n0 = blockIdx.x * 32;
    const int t = threadIdx.x;
    const int wid = t >> 6, lane = t & 63, ln = lane & 15, okt = lane >> 4;

    __shared__ __align__(16) _Float16 s_xsh[32][68];
    __shared__ __align__(16) _Float16 s_xv01[32][66];
    __shared__ __align__(16) _Float16 s_xv2[32][34];
    __shared__ __align__(16) _Float16 s_ash[32][104];     // ags fp16
    __shared__ __align__(16) _Float16 s_avTh[32][3][40];  // agv^T fp16
    __shared__ float s_hs2[32][100];
    __shared__ float s_hv2[96][34];                       // rows (k*32+n)
    __shared__ float s_ag[32][160];

    for (int i = t; i < 32 * 160; i += 256)
        ((float*)s_ag)[i] = agg[(size_t)n0 * 160 + i];
    for (int i = t; i < 32 * 40; i += 256) {
        int n = i / 40, q = i - n * 40;
        f32x4 f4 = *((const f32x4*)nf + (size_t)(n0 + n) * 40 + q);
        if (q < 16) {
            #pragma unroll
            for (int j = 0; j < 4; ++j) s_xsh[n][q * 4 + j] = (_Float16)f4[j];
        } else {
            #pragma unroll
            for (int j = 0; j < 4; ++j) {
                int d = (q - 16) * 4 + j, u = d / 3, k = d - u * 3;
                if (k < 2) s_xv01[n][u * 2 + k] = (_Float16)f4[j];
                else       s_xv2[n][u] = (_Float16)f4[j];
            }
        }
    }
    __syncthreads();
    // folded agglin (linear commuted past segment_sum)
    #pragma unroll
    for (int r = 0; r < 12; ++r) {
        int o = t + r * 256;
        int n = o / 96, q = o - n * 96;
        float a = 0.f;
        #pragma unroll
        for (int u = 0; u < 64; ++u) a = fmaf(s_ag[n][u], Wlms[u * 96 + q], a);
        s_ash[n][q] = (_Float16)(a * 0.125f);
    }
    #pragma unroll
    for (int r = 0; r < 12; ++r) {
        int o = t + r * 256;
        int n = o / 96, q = o - n * 96, k = q >> 5, v = q & 31;
        float a = 0.f;
        #pragma unroll
        for (int u = 0; u < 32; ++u) a = fmaf(s_ag[n][64 + u * 3 + k], Wlmv[u * 32 + v], a);
        s_avTh[n][k][v] = (_Float16)(a * 0.17677669529663687f);
    }
    __syncthreads();

    f32x4 acc[6] = {};

    if (wid < 2) {
        // GEMM A: hs2[32 x 96]; all 2 M-tiles, N-tiles wid*3..wid*3+2, K=7168
        const unsigned short* wb = wA + (size_t)(wid * 48 + ln) * 7168;
        #pragma unroll 2
        for (int kb = 0; kb < 64; ++kb) {          // ss region: u = kb, K = kb*96 + p*32 + okt*8
            _Float16 x0 = s_xsh[ln][kb];
            _Float16 x1 = s_xsh[16 + ln][kb];
            #pragma unroll
            for (int p = 0; p < 3; ++p) {
                const int ko = kb * 96 + p * 32 + okt * 8;
                const int v0 = p * 32 + okt * 8;
                h8 b0 = *(const h8*)(wb + ko);
                h8 b1 = *(const h8*)(wb + 16 * 7168 + ko);
                h8 b2 = *(const h8*)(wb + 32 * 7168 + ko);
                h8 a0 = rank1(x0, (const h2*)&s_ash[ln][v0]);
                h8 a1 = rank1(x1, (const h2*)&s_ash[16 + ln][v0]);
                acc[0] = MFMA(a0, b0, acc[0]); acc[1] = MFMA(a0, b1, acc[1]); acc[2] = MFMA(a0, b2, acc[2]);
                acc[3] = MFMA(a1, b0, acc[3]); acc[4] = MFMA(a1, b1, acc[4]); acc[5] = MFMA(a1, b2, acc[5]);
            }
        }
        #pragma unroll 4
        for (int ks = 0; ks < 32; ++ks) {          // vv region: u = ks, v0 = okt*8
            const int ko = 6144 + ks * 32 + okt * 8;
            const int v0 = okt * 8;
            h8 b0 = *(const h8*)(wb + ko);
            h8 b1 = *(const h8*)(wb + 16 * 7168 + ko);
            h8 b2 = *(const h8*)(wb + 32 * 7168 + ko);
            h2 xa = *(const h2*)&s_xv01[ln][ks * 2];
            h2 xb = *(const h2*)&s_xv01[16 + ln][ks * 2];
            h8 a0 = rank3(xa[0], xa[1], s_xv2[ln][ks],
                          (const h2*)&s_avTh[ln][0][v0], (const h2*)&s_avTh[ln][1][v0],
                          (const h2*)&s_avTh[ln][2][v0]);
            h8 a1 = rank3(xb[0], xb[1], s_xv2[16 + ln][ks],
                          (const h2*)&s_avTh[16 + ln][0][v0], (const h2*)&s_avTh[16 + ln][1][v0],
                          (const h2*)&s_avTh[16 + ln][2][v0]);
            acc[0] = MFMA(a0, b0, acc[0]); acc[1] = MFMA(a0, b1, acc[1]); acc[2] = MFMA(a0, b2, acc[2]);
            acc[3] = MFMA(a1, b0, acc[3]); acc[4] = MFMA(a1, b1, acc[4]); acc[5] = MFMA(a1, b2, acc[5]);
        }
    } else {
        // GEMM B: hv2[(k,n)=96 x 32]; all 6 M-tiles, N-tile (wid-2), K=5120
        const unsigned short* bp = wB + (size_t)((wid - 2) * 16 + ln) * 5120;
        #pragma unroll 2
        for (int ks = 0; ks < 64; ++ks) {          // sv region: u = ks, v0 = okt*8
            const int ko = ks * 32 + okt * 8;
            const int v0 = okt * 8;
            h8 b = *(const h8*)(bp + ko);
            #pragma unroll
            for (int m = 0; m < 6; ++m) {
                const int k = m >> 1, n = ((m & 1) << 4) + ln;
                h8 a = rank1(s_xsh[n][ks], (const h2*)&s_avTh[n][k][v0]);
                acc[m] = MFMA(a, b, acc[m]);
            }
        }
        #pragma unroll 2
        for (int kb = 0; kb < 32; ++kb) {          // vs region: u = kb
            _Float16 xa[6];
            #pragma unroll
            for (int m = 0; m < 6; ++m) {
                const int k = m >> 1, n = ((m & 1) << 4) + ln;
                xa[m] = (k < 2) ? s_xv01[n][kb * 2 + k] : s_xv2[n][kb];
            }
            #pragma unroll
            for (int p = 0; p < 3; ++p) {
                const int ko = 2048 + kb * 96 + p * 32 + okt * 8;
                const int v0 = p * 32 + okt * 8;
                h8 b = *(const h8*)(bp + ko);
                #pragma unroll
                for (int m = 0; m < 6; ++m) {
                    const int n = ((m & 1) << 4) + ln;
                    h8 a = rank1(xa[m], (const h2*)&s_ash[n][v0]);
                    acc[m] = MFMA(a, b, acc[m]);
                }
            }
        }
    }

    // ---- store C tiles ----
    if (wid < 2) {
        #pragma unroll
        for (int m = 0; m < 2; ++m)
            #pragma unroll
            for (int j = 0; j < 3; ++j)
                #pragma unroll
                for (int r = 0; r < 4; ++r)
                    s_hs2[m * 16 + okt * 4 + r][wid * 48 + j * 16 + ln] = acc[m * 3 + j][r];
    } else {
        #pragma unroll
        for (int m = 0; m < 6; ++m)
            #pragma unroll
            for (int r = 0; r < 4; ++r)
                s_hv2[m * 16 + okt * 4 + r][(wid - 2) * 16 + ln] = acc[m][r];
    }
    __syncthreads();
    // gate transform in place: hs cols<64 -> silu, cols>=64 -> sigmoid
    for (int i = t; i < 32 * 96; i += 256) {
        int n = i / 96, w = i - n * 96;
        float h = s_hs2[n][w];
        s_hs2[n][w] = (w < 64) ? h * sigf(h) : sigf(h);
    }
    __syncthreads();
    for (int i = t; i < 96 * 32; i += 256) {
        int R = i >> 5, w2 = i & 31, n = R & 31;
        s_hv2[R][w2] *= s_hs2[n][64 + w2];
    }
    __syncthreads();
    // final irrep linear + residual
    for (int i = t; i < 32 * 64; i += 256) {
        int n = i >> 6, w = i & 63;
        float a = 0.f;
        #pragma unroll
        for (int u = 0; u < 64; ++u) a = fmaf(s_hs2[n][u], Wls[u * 64 + w], a);
        size_t o = (size_t)(n0 + n) * 160 + w;
        out[o] = nf[o] + a * 0.125f;
    }
    for (int i = t; i < 32 * 96; i += 256) {
        int n = i / 96, wk = i - n * 96, w = wk / 3, k = wk - w * 3;
        float a = 0.f;
        #pragma unroll
        for (int u = 0; u < 32; ++u) a = fmaf(s_hv2[k * 32 + n][u], Wlv[u * 32 + w], a);
        size_t o = (size_t)(n0 + n) * 160 + 64 + wk;
        out[o] = nf[o] + a * 0.17677669529663687f;
    }
}

extern "C" void kernel_launch(void* const* d_in, const int* in_sizes, int n_in,
                              void* d_out, int out_size, void* d_ws, size_t ws_size,
                              hipStream_t stream) {
    const float* nf   = (const float*)d_in[0];
    const float* ea   = (const float*)d_in[1];
    const int*   eidx = (const int*)d_in[3];
    const float* Wmss = (const float*)d_in[4];
    const float* Wmvv = (const float*)d_in[5];
    const float* Wmsv = (const float*)d_in[6];
    const float* Wmvs = (const float*)d_in[7];
    const float* Wlms = (const float*)d_in[8];
    const float* Wlmv = (const float*)d_in[9];
    const float* Wuss = (const float*)d_in[10];
    const float* Wuvv = (const float*)d_in[11];
    const float* Wusv = (const float*)d_in[12];
    const float* Wuvs = (const float*)d_in[13];
    const float* Wlus = (const float*)d_in[14];
    const float* Wluv = (const float*)d_in[15];
    float* out = (float*)d_out;

    float* agg = (float*)d_ws;                          // [NN,160]
    unsigned short* wAm = (unsigned short*)(agg + (size_t)NN * 160);
    unsigned short* wBm = wAm + 96 * 768;
    unsigned short* wAu = wBm + 32 * 768;
    unsigned short* wBu = wAu + (size_t)96 * 7168;
    int* counts = (int*)(wBu + (size_t)32 * 5120);      // [NN] -> becomes cursor
    int* perm   = counts + NN;                          // [NE]

    const float NSM = 0.03608439182435161f;   // 1/sqrt(768)
    const float NSU = 0.011811365506297619f;  // 1/sqrt(7168)
    const float NVU = 0.013975424859373686f;  // 1/sqrt(5120)
    const float S3  = 0.57735026918962576f;   // 1/sqrt(3)

    hipMemsetAsync(agg, 0, (size_t)NN * 160 * sizeof(float), stream);
    hipMemsetAsync(counts, 0, (size_t)NN * sizeof(int), stream);

    prep_kernel<<<(96 * 768 + 255) / 256, 256, 0, stream>>>(Wmss, Wmvv, 512, 768, 96, NSM, NSM * S3, wAm, 96 * 768);
    prep_kernel<<<(32 * 768 + 255) / 256, 256, 0, stream>>>(Wmsv, Wmvs, 512, 768, 32, NSM, NSM, wBm, 32 * 768);
    prep_kernel<<<(96 * 7168 + 255) / 256, 256, 0, stream>>>(Wuss, Wuvv, 6144, 7168, 96, NSU, NSU * S3, wAu, 96 * 7168);
    prep_kernel<<<(32 * 5120 + 255) / 256, 256, 0, stream>>>(Wusv, Wuvs, 2048, 5120, 32, NVU, NVU, wBu, 32 * 5120);

    hist_kernel<<<(NE + 255) / 256, 256, 0, stream>>>(eidx, counts);
    scan_kernel<<<1, 1024, 0, stream>>>(counts);
    scatter_kernel<<<(NE + 255) / 256, 256, 0, stream>>>(eidx, counts, perm);

    msg_kernel<<<NE / 64, 256, 0, stream>>>(nf, ea, eidx, perm, wAm, wBm, agg);
    upd_kernel<<<NN / 32, 256, 0, stream>>>(nf, agg, wAu, wBu, Wlms, Wlmv, Wlus, Wluv, out);
}